// Round 15
// baseline (1169.421 us; speedup 1.0000x reference)
//
#include <hip/hip_runtime.h>
#include <hip/hip_bf16.h>
#include <cstdint>

#define BB 128
#define TT 20
#define VV 10000
#define DD 1024
#define NHH 8
#define DHH 128
#define NN 196

typedef float f32x4 __attribute__((ext_vector_type(4)));
typedef __bf16 bf16x8 __attribute__((ext_vector_type(8)));
typedef unsigned int u32x4 __attribute__((ext_vector_type(4)));
typedef unsigned int u32x2 __attribute__((ext_vector_type(2)));

__device__ __forceinline__ unsigned short f2bf(float x) {
  unsigned u = __float_as_uint(x);
  u += 0x7FFFu + ((u >> 16) & 1u);
  return (unsigned short)(u >> 16);
}
__device__ __forceinline__ float bf2f(unsigned short h) {
  return __uint_as_float(((unsigned)h) << 16);
}
__device__ __forceinline__ float sigm(float x) { return 1.f / (1.f + __expf(-x)); }
__device__ __forceinline__ unsigned pk2(float lo, float hi) {
  return (unsigned)f2bf(lo) | ((unsigned)f2bf(hi) << 16);
}
__device__ __forceinline__ int xcd_swz(int orig, int nb) {
  int q = nb >> 3, r = nb & 7;
  int x = orig & 7, i = orig >> 3;
  return (x < r ? x * (q + 1) : r * (q + 1) + (x - r) * q) + i;
}
__device__ __forceinline__ void gl16(const void* g, void* l) {
  __builtin_amdgcn_global_load_lds((const __attribute__((address_space(1))) void*)g,
                                   (__attribute__((address_space(3))) void*)l, 16, 0, 0);
}

template<int N> __device__ __forceinline__ void waitvm() {
  if constexpr (N == 0)       asm volatile("s_waitcnt vmcnt(0)" ::: "memory");
  else if constexpr (N == 3)  asm volatile("s_waitcnt vmcnt(3)" ::: "memory");
  else if constexpr (N == 5)  asm volatile("s_waitcnt vmcnt(5)" ::: "memory");
  else if constexpr (N == 6)  asm volatile("s_waitcnt vmcnt(6)" ::: "memory");
  else if constexpr (N == 8)  asm volatile("s_waitcnt vmcnt(8)" ::: "memory");
  else if constexpr (N == 10) asm volatile("s_waitcnt vmcnt(10)" ::: "memory");
  else if constexpr (N == 12) asm volatile("s_waitcnt vmcnt(12)" ::: "memory");
  else if constexpr (N == 16) asm volatile("s_waitcnt vmcnt(16)" ::: "memory");
}
#define LGKM0()  asm volatile("s_waitcnt lgkmcnt(0)" ::: "memory")
#define SCHED0() __builtin_amdgcn_sched_barrier(0)

// ---- unified deep-pipelined GEMM: C[M,N] = A[M,K] @ W[N,:]^T, BM in {64,128}, BK=64.
// MODE 0: fp32 out (ldc=N)
// MODE 2: vocab batched rows=(t*128+b) + mask
// MODE 3: gates + Eall add + fused LSTM (W 32-col gate-interleaved)
// MODE 4: aoa + fused GLU (W 32-col half-interleaved)
// RF: row-fastest wg mapping. K2: 2 K-tiles/iter, single barrier (DEP=6, stage dist 4).
template<int BM, int BN, int MODE, int DEP, bool RF, bool K2 = false>
__launch_bounds__(256)
__global__ void gemmp(const unsigned short* __restrict__ A, int lda,
                      const unsigned short* __restrict__ W, int ldw,
                      int nkt, int N, int ncol,
                      const float* __restrict__ bias,
                      float* __restrict__ outF, unsigned short* __restrict__ outB,
                      float* __restrict__ mbuf, const float* __restrict__ meanf,
                      unsigned short* __restrict__ xaoa, unsigned short* __restrict__ xn2,
                      const int* __restrict__ lengths)
{
  constexpr int SZA = BM * 128;
  constexpr int SZB = BN * 128;
  constexpr int NJ = BN / 16;
  constexpr int MI = BM / 64;
  constexpr int S = BM / 32 + BN / 32;
  __shared__ char smem[DEP * (SZA + SZB)];

  const int nb = gridDim.x;
  const int wg = xcd_swz(blockIdx.x, nb);
  int xi, rowt;
  if (RF) { const int nrow = nb / ncol; rowt = wg % nrow; xi = wg / nrow; }
  else    { xi = wg % ncol; rowt = wg / ncol; }
  const int colbase = xi * BN;
  const int rowbase = rowt * BM;
  const int tid = threadIdx.x;
  const int lane = tid & 63, wv = tid >> 6;
  const int wrow = wv * (BM / 4);
  const int lr = lane & 15;
  const int srow = lane >> 3;
  const int schunk = ((lane & 7) ^ srow) * 8;

  auto stage = [&](int t, int buf) {
    char* sA = smem + buf * (SZA + SZB);
    char* sB = sA + SZA;
    const int k0 = t << 6;
    #pragma unroll
    for (int s = 0; s < BM / 32; ++s) {
      const int rb = s * 32 + wv * 8;
      gl16(A + (size_t)(rowbase + rb + srow) * lda + k0 + schunk, sA + rb * 128);
    }
    #pragma unroll
    for (int s = 0; s < BN / 32; ++s) {
      const int rb = s * 32 + wv * 8;
      int br = colbase + rb + srow;
      if (MODE == 2) br = br < N ? br : N - 1;
      gl16(W + (size_t)br * ldw + k0 + schunk, sB + rb * 128);
    }
  };

  f32x4 acc[MI][NJ];
  const f32x4 zero = {0.f, 0.f, 0.f, 0.f};
  #pragma unroll
  for (int i = 0; i < MI; ++i)
    #pragma unroll
    for (int j = 0; j < NJ; ++j) acc[i][j] = zero;

  #pragma unroll
  for (int t = 0; t < (K2 ? 4 : DEP); ++t) stage(t, t);

  const int axor = (lr & 7) << 4;
  const int ccol = (lane >> 4) * 16;

  if constexpr (K2) {
    for (int i = 0; i < nkt; i += 2) {
      if (i + 2 < nkt) waitvm<2 * S>(); else waitvm<0>();
      __builtin_amdgcn_s_barrier();     // protects bufs read in iteration n-1
      SCHED0();
      if (i + 4 < nkt) {
        stage(i + 4, (i + 4) % DEP);
        stage(i + 5, (i + 5) % DEP);
      }
      bf16x8 af[2][MI][2], bfr[2][NJ][2];
      #pragma unroll
      for (int u = 0; u < 2; ++u) {
        const char* sA = smem + ((i + u) % DEP) * (SZA + SZB);
        const char* sB = sA + SZA;
        #pragma unroll
        for (int ii = 0; ii < MI; ++ii)
          #pragma unroll
          for (int kk = 0; kk < 2; ++kk)
            af[u][ii][kk] = *reinterpret_cast<const bf16x8*>(
                sA + (wrow + ii * 16 + lr) * 128 + ((kk * 64 + ccol) ^ axor));
        #pragma unroll
        for (int j = 0; j < NJ; ++j)
          #pragma unroll
          for (int kk = 0; kk < 2; ++kk)
            bfr[u][j][kk] = *reinterpret_cast<const bf16x8*>(
                sB + (j * 16 + lr) * 128 + ((kk * 64 + ccol) ^ axor));
      }
      LGKM0();
      SCHED0();
      #pragma unroll
      for (int u = 0; u < 2; ++u)
        #pragma unroll
        for (int kk = 0; kk < 2; ++kk)
          #pragma unroll
          for (int ii = 0; ii < MI; ++ii)
            #pragma unroll
            for (int j = 0; j < NJ; ++j)
              acc[ii][j] = __builtin_amdgcn_mfma_f32_16x16x32_bf16(af[u][ii][kk], bfr[u][j][kk], acc[ii][j], 0, 0, 0);
    }
  } else {
    int buf = 0;
    for (int i = 0; i < nkt; ++i) {
      const int rem = nkt - 1 - i;
      if (rem >= DEP - 1)            waitvm<S * (DEP - 1)>();
      else if (DEP > 2 && rem == 1)  waitvm<S>();
      else                           waitvm<0>();
      __builtin_amdgcn_s_barrier();
      SCHED0();
      const char* sA = smem + buf * (SZA + SZB);
      const char* sB = sA + SZA;
      bf16x8 af[MI][2], bfr[NJ][2];
      #pragma unroll
      for (int ii = 0; ii < MI; ++ii)
        #pragma unroll
        for (int kk = 0; kk < 2; ++kk)
          af[ii][kk] = *reinterpret_cast<const bf16x8*>(
              sA + (wrow + ii * 16 + lr) * 128 + ((kk * 64 + ccol) ^ axor));
      #pragma unroll
      for (int j = 0; j < NJ; ++j)
        #pragma unroll
        for (int kk = 0; kk < 2; ++kk)
          bfr[j][kk] = *reinterpret_cast<const bf16x8*>(
              sB + (j * 16 + lr) * 128 + ((kk * 64 + ccol) ^ axor));
      LGKM0();
      SCHED0();
      __builtin_amdgcn_s_barrier();
      SCHED0();
      if (i + DEP < nkt) stage(i + DEP, buf);
      #pragma unroll
      for (int kk = 0; kk < 2; ++kk)
        #pragma unroll
        for (int ii = 0; ii < MI; ++ii)
          #pragma unroll
          for (int j = 0; j < NJ; ++j)
            acc[ii][j] = __builtin_amdgcn_mfma_f32_16x16x32_bf16(af[ii][kk], bfr[j][kk], acc[ii][j], 0, 0, 0);
      buf = (buf == DEP - 1) ? 0 : buf + 1;
    }
  }

  const int rg4 = (lane >> 4) * 4;

  if constexpr (MODE == 0) {
    #pragma unroll
    for (int ii = 0; ii < MI; ++ii)
      #pragma unroll
      for (int j = 0; j < NJ; ++j) {
        const int gcol = colbase + j * 16 + lr;
        #pragma unroll
        for (int r = 0; r < 4; ++r)
          outF[(size_t)(rowbase + wrow + ii * 16 + rg4 + r) * N + gcol] = acc[ii][j][r];
      }
  } else if constexpr (MODE == 2) {
    #pragma unroll
    for (int ii = 0; ii < MI; ++ii)
      #pragma unroll
      for (int j = 0; j < NJ; ++j) {
        const int gcol = colbase + j * 16 + lr;
        if (gcol >= N) continue;
        const float bv = bias[gcol];
        #pragma unroll
        for (int r = 0; r < 4; ++r) {
          const int gr = rowbase + wrow + ii * 16 + rg4 + r;   // t*128 + b
          const int tt = gr >> 7, bb = gr & 127;
          outF[((size_t)bb * TT + tt) * VV + gcol] =
              (tt < lengths[bb]) ? acc[ii][j][r] + bv : 0.f;
        }
      }
  } else if constexpr (MODE == 3) {
    const float b0 = bias[colbase + lr], b1 = bias[colbase + 16 + lr];
    float a0[MI][4], a1[MI][4];
    #pragma unroll
    for (int ii = 0; ii < MI; ++ii)
      #pragma unroll
      for (int r = 0; r < 4; ++r) {
        const int grow = rowbase + wrow + ii * 16 + rg4 + r;
        a0[ii][r] = acc[ii][0][r] + b0 + outF[(size_t)grow * 4096 + colbase + lr];
        a1[ii][r] = acc[ii][1][r] + b1 + outF[(size_t)grow * 4096 + colbase + 16 + lr];
      }
    const int d = (colbase >> 2) + (lr & 7);
    #pragma unroll
    for (int ii = 0; ii < MI; ++ii)
      #pragma unroll
      for (int r = 0; r < 4; ++r) {
        const float fg = __shfl_xor(a0[ii][r], 8);
        const float og = __shfl_xor(a1[ii][r], 8);
        if (lr < 8) {
          const int grow = rowbase + wrow + ii * 16 + rg4 + r;
          const float m2 = sigm(fg) * mbuf[(size_t)grow * DD + d] + sigm(a0[ii][r]) * tanhf(a1[ii][r]);
          const float h2 = sigm(og) * tanhf(m2);
          mbuf[(size_t)grow * DD + d] = m2;
          const unsigned short hb = f2bf(h2);
          xaoa[(size_t)grow * 2048 + 1024 + d] = hb;
          xn2[(size_t)grow * 2048 + 1024 + d] = hb;
        }
      }
  } else {  // MODE 4: aoa + GLU
    const int d = (colbase >> 1) + lr;
    const float b0 = bias[colbase + lr], b1 = bias[colbase + 16 + lr];
    #pragma unroll
    for (int ii = 0; ii < MI; ++ii)
      #pragma unroll
      for (int r = 0; r < 4; ++r) {
        const int grow = rowbase + wrow + ii * 16 + rg4 + r;
        const float av1 = acc[ii][0][r] + b0;
        const float av2 = acc[ii][1][r] + b1;
        const float c2 = av1 * sigm(av2);
        outB[(size_t)grow * DD + d] = f2bf(c2);
        xn2[(size_t)grow * 2048 + d] = f2bf(meanf[(size_t)grow * DD + d] + c2);
      }
  }
}

// ---- shared 128x128 DEP=2 nkt=16 GEMM core for the merged KV+Eall kernel ----
__device__ __forceinline__ void gemm_core128(const unsigned short* __restrict__ A, int lda,
                                             const unsigned short* __restrict__ W, int ldw,
                                             int rowbase, int colbase, char* smem,
                                             f32x4 (&acc)[2][8])
{
  constexpr int SZA = 128 * 128, SZB = 128 * 128;
  const int tid = threadIdx.x;
  const int lane = tid & 63, wv = tid >> 6;
  const int wrow = wv * 32;
  const int lr = lane & 15;
  const int srow = lane >> 3;
  const int schunk = ((lane & 7) ^ srow) * 8;

  auto stage = [&](int t, int buf) {
    char* sA = smem + buf * (SZA + SZB);
    char* sB = sA + SZA;
    const int k0 = t << 6;
    #pragma unroll
    for (int s = 0; s < 4; ++s) {
      const int rb = s * 32 + wv * 8;
      gl16(A + (size_t)(rowbase + rb + srow) * lda + k0 + schunk, sA + rb * 128);
    }
    #pragma unroll
    for (int s = 0; s < 4; ++s) {
      const int rb = s * 32 + wv * 8;
      gl16(W + (size_t)(colbase + rb + srow) * ldw + k0 + schunk, sB + rb * 128);
    }
  };

  const f32x4 zero = {0.f, 0.f, 0.f, 0.f};
  #pragma unroll
  for (int i = 0; i < 2; ++i)
    #pragma unroll
    for (int j = 0; j < 8; ++j) acc[i][j] = zero;

  stage(0, 0); stage(1, 1);
  const int axor = (lr & 7) << 4;
  const int ccol = (lane >> 4) * 16;
  int buf = 0;
  for (int i = 0; i < 16; ++i) {
    if (i < 15) waitvm<8>(); else waitvm<0>();
    __builtin_amdgcn_s_barrier();
    SCHED0();
    const char* sA = smem + buf * (SZA + SZB);
    const char* sB = sA + SZA;
    bf16x8 af[2][2], bfr[8][2];
    #pragma unroll
    for (int ii = 0; ii < 2; ++ii)
      #pragma unroll
      for (int kk = 0; kk < 2; ++kk)
        af[ii][kk] = *reinterpret_cast<const bf16x8*>(
            sA + (wrow + ii * 16 + lr) * 128 + ((kk * 64 + ccol) ^ axor));
    #pragma unroll
    for (int j = 0; j < 8; ++j)
      #pragma unroll
      for (int kk = 0; kk < 2; ++kk)
        bfr[j][kk] = *reinterpret_cast<const bf16x8*>(
            sB + (j * 16 + lr) * 128 + ((kk * 64 + ccol) ^ axor));
    LGKM0();
    SCHED0();
    __builtin_amdgcn_s_barrier();
    SCHED0();
    if (i + 2 < 16) stage(i + 2, buf);
    #pragma unroll
    for (int kk = 0; kk < 2; ++kk)
      #pragma unroll
      for (int ii = 0; ii < 2; ++ii)
        #pragma unroll
        for (int j = 0; j < 8; ++j)
          acc[ii][j] = __builtin_amdgcn_mfma_f32_16x16x32_bf16(af[ii][kk], bfr[j][kk], acc[ii][j], 0, 0, 0);
    buf ^= 1;
  }
}

// ---- merged KV projection (blocks 0..3135) + Eall GEMM (blocks 3136..3775) ----
__launch_bounds__(256)
__global__ void kv_eall_kernel(const unsigned short* __restrict__ encb,
                               const unsigned short* __restrict__ Wkv,
                               const float* __restrict__ bkv,
                               unsigned short* __restrict__ KV,
                               const unsigned short* __restrict__ embAll,
                               const unsigned short* __restrict__ WcatI,
                               float* __restrict__ Eall)
{
  __shared__ char smem[2 * (128 * 128 + 128 * 128)];   // 64 KB
  f32x4 acc[2][8];
  const int tid = threadIdx.x;
  const int lane = tid & 63, wv = tid >> 6;
  const int wrow = wv * 32, lr = lane & 15;
  const int rg4 = (lane >> 4) * 4;

  if (blockIdx.x < 3136) {
    // KV: col-fast (A-reuse), 196 rowtiles x 16 coltiles
    const int wg = xcd_swz(blockIdx.x, 3136);
    const int xi = wg % 16, rowt = wg / 16;
    const int colbase = xi * 128, rowbase = rowt * 128;
    gemm_core128(encb, 1024, Wkv, 1024, rowbase, colbase, smem, acc);
    #pragma unroll
    for (int ii = 0; ii < 2; ++ii)
      #pragma unroll
      for (int j = 0; j < 8; ++j) {
        const int gcol = colbase + j * 16 + lr;
        const float bv = bkv[gcol];
        #pragma unroll
        for (int r = 0; r < 4; ++r)
          KV[(size_t)(rowbase + wrow + ii * 16 + rg4 + r) * 2048 + gcol] = f2bf(acc[ii][j][r] + bv);
      }
  } else {
    // Eall: row-fast (W-reuse), 20 rowtiles x 32 coltiles
    const int wg = xcd_swz(blockIdx.x - 3136, 640);
    const int rowt = wg % 20, xi = wg / 20;
    const int colbase = xi * 128, rowbase = rowt * 128;
    gemm_core128(embAll, 1024, WcatI, 3072, rowbase, colbase, smem, acc);
    #pragma unroll
    for (int ii = 0; ii < 2; ++ii)
      #pragma unroll
      for (int j = 0; j < 8; ++j) {
        const int gcol = colbase + j * 16 + lr;
        #pragma unroll
        for (int r = 0; r < 4; ++r)
          Eall[(size_t)(rowbase + wrow + ii * 16 + rg4 + r) * 4096 + gcol] = acc[ii][j][r];
      }
  }
}

// ---- attention (grid 1024 = (b,h)), wave-parallel softmax, dual-acc PV ----
__launch_bounds__(256)
__global__ void attn_kernel(const float* __restrict__ qbuf, const float* __restrict__ bq,
                            const unsigned short* __restrict__ KV, unsigned short* __restrict__ xaoa) {
  const int bh = blockIdx.x, b = bh >> 3, h = bh & 7;
  const int tid = threadIdx.x;
  const int lane = tid & 63, wv = tid >> 6;
  __shared__ float qs[DHH];
  __shared__ float sc[NN + 4];
  __shared__ float pvred[2][DHH];
  __shared__ float redm[4], reds[4];
  if (tid < DHH)
    qs[tid] = bq[h * DHH + tid] + qbuf[(size_t)b * DD + h * DHH + tid];
  __syncthreads();
  if (tid < NN) {
    const unsigned short* kr = KV + ((size_t)(b * NN + tid)) * 2048 + h * DHH;
    float a = 0.f;
    #pragma unroll
    for (int j = 0; j < 16; ++j) {
      u32x4 kk = *reinterpret_cast<const u32x4*>(kr + j * 8);
      #pragma unroll
      for (int w = 0; w < 4; ++w) {
        a += bf2f((unsigned short)(kk[w] & 0xffffu)) * qs[j * 8 + w * 2]
           + bf2f((unsigned short)(kk[w] >> 16)) * qs[j * 8 + w * 2 + 1];
      }
    }
    sc[tid] = a * 0.08838834764831845f;
  }
  __syncthreads();
  float v = (tid < NN) ? sc[tid] : -1e30f;
  #pragma unroll
  for (int o = 32; o; o >>= 1) v = fmaxf(v, __shfl_xor(v, o));
  if (lane == 0) redm[wv] = v;
  __syncthreads();
  const float mx = fmaxf(fmaxf(redm[0], redm[1]), fmaxf(redm[2], redm[3]));
  float e = 0.f;
  if (tid < NN) { e = __expf(sc[tid] - mx); sc[tid] = e; }
  float s = e;
  #pragma unroll
  for (int o = 32; o; o >>= 1) s += __shfl_xor(s, o);
  if (lane == 0) reds[wv] = s;
  __syncthreads();
  const float inv = 1.f / (reds[0] + reds[1] + reds[2] + reds[3]);
  const int d = tid & 127, half = tid >> 7;
  const unsigned short* vr = KV + ((size_t)(b * NN + half * 98)) * 2048 + 1024 + h * DHH + d;
  const float* pr = sc + half * 98;
  float a0 = 0.f, a1 = 0.f;
  #pragma unroll 7
  for (int n = 0; n < 98; n += 2) {
    a0 += pr[n]     * bf2f(vr[(size_t)n * 2048]);
    a1 += pr[n + 1] * bf2f(vr[(size_t)(n + 1) * 2048]);
  }
  pvred[half][d] = a0 + a1;
  __syncthreads();
  if (tid < DHH)
    xaoa[(size_t)b * 2048 + h * DHH + tid] = f2bf((pvred[0][tid] + pvred[1][tid]) * inv);
}

// ---- fused prep: weights/bias/embedding/meanconv+init, one launch, range-dispatched ----
// [0,12288) wcatI | [12288,13312) Wq | [13312,17408) waoaI | [17408,19456) kvw |
// [19456,19472) bias | [19472,22032) emb | [22032,22544) meanconv + mbuf/x2 init
__launch_bounds__(256)
__global__ void prep_kernel(const float* __restrict__ W_ih, const float* __restrict__ W_hh,
                            const float* __restrict__ Wq, const float* __restrict__ W_aoa,
                            const float* __restrict__ Wk, const float* __restrict__ Wv,
                            const float* __restrict__ b_ih, const float* __restrict__ b_hh,
                            const float* __restrict__ b_aoa, const float* __restrict__ bk,
                            const float* __restrict__ bv,
                            const float* __restrict__ embed_W, const int* __restrict__ captions,
                            const float* __restrict__ enc,
                            unsigned short* __restrict__ WcatI, unsigned short* __restrict__ Wq_b,
                            unsigned short* __restrict__ WaoaI, unsigned short* __restrict__ Wkv_b,
                            float* __restrict__ bcombI, float* __restrict__ baoaI,
                            float* __restrict__ bkv,
                            unsigned short* __restrict__ embAll,
                            float* __restrict__ meanf, unsigned short* __restrict__ encb,
                            float* __restrict__ mbuf, unsigned short* __restrict__ x2_0)
{
  const int bid = blockIdx.x, tid = threadIdx.x;
  if (bid < 12288) {
    int i = bid * 256 + tid;
    int rp = i / 768, c4 = (i - rp * 768) * 4;
    int rem = rp & 31, g = rem >> 3, d = (rp >> 5) * 8 + (rem & 7);
    int orig = g * 1024 + d;
    const float* src = (c4 < 2048) ? (W_ih + (size_t)orig * 2048 + c4)
                                   : (W_hh + (size_t)orig * 1024 + (c4 - 2048));
    f32x4 vv = *reinterpret_cast<const f32x4*>(src);
    u32x2 o = { pk2(vv[0], vv[1]), pk2(vv[2], vv[3]) };
    *reinterpret_cast<u32x2*>(WcatI + (size_t)rp * 3072 + c4) = o;
  } else if (bid < 13312) {
    int i = (bid - 12288) * 256 + tid;
    f32x4 vv = *reinterpret_cast<const f32x4*>(Wq + (size_t)i * 4);
    u32x2 o = { pk2(vv[0], vv[1]), pk2(vv[2], vv[3]) };
    *reinterpret_cast<u32x2*>(Wq_b + (size_t)i * 4) = o;
  } else if (bid < 17408) {
    int i = (bid - 13312) * 256 + tid;
    int rp = i >> 9, c4 = (i & 511) * 4;
    int rem = rp & 31, half = rem >> 4, d = (rp >> 5) * 16 + (rem & 15);
    int orig = half * 1024 + d;
    f32x4 vv = *reinterpret_cast<const f32x4*>(W_aoa + (size_t)orig * 2048 + c4);
    u32x2 o = { pk2(vv[0], vv[1]), pk2(vv[2], vv[3]) };
    *reinterpret_cast<u32x2*>(WaoaI + (size_t)rp * 2048 + c4) = o;
  } else if (bid < 19456) {
    int i = (bid - 17408) * 256 + tid;
    int row = i >> 8, c4 = (i & 255) << 2;
    const float* src = (row < 1024) ? (Wk + (size_t)row * 1024 + c4)
                                    : (Wv + (size_t)(row - 1024) * 1024 + c4);
    f32x4 vv = *reinterpret_cast<const f32x4*>(src);
    u32x2 o = { pk2(vv[0], vv[1]), pk2(vv[2], vv[3]) };
    *reinterpret_cast<u32x2*>(Wkv_b + (size_t)row * 1024 + c4) = o;
  } else if (bid < 19472) {
    int i = (bid - 19456) * 256 + tid;
    {
      int rem = i & 31, g = rem >> 3, d = (i >> 5) * 8 + (rem & 7);
      int orig = g * 1024 + d;
      bcombI[i] = b_ih[orig] + b_hh[orig];
    }
    if (i < 2048) {
      int rem = i & 31, half = rem >> 4, d = (i >> 5) * 16 + (rem & 15);
      baoaI[i] = b_aoa[half * 1024 + d];
      bkv[i] = (i < 1024) ? bk[i] : bv[i - 1024];
    }
  } else if (bid < 22032) {
    int i = (bid - 19472) * 256 + tid;
    int j4 = (i & 255) << 2, b = (i >> 8) & 127, t = i >> 15;
    int tok = captions[b * TT + t];
    f32x4 vv = *reinterpret_cast<const f32x4*>(embed_W + (size_t)tok * DD + j4);
    u32x2 o = { pk2(vv[0], vv[1]), pk2(vv[2], vv[3]) };
    *reinterpret_cast<u32x2*>(embAll + ((size_t)t * BB + b) * DD + j4) = o;
  } else {
    // meanconv + init: 512 blocks, block=(b, 256-wide d group)
    int rb = bid - 22032;
    int b = rb >> 2, d = (rb & 3) * 256 + tid;
    const float* p = enc + (size_t)b * NN * DD + d;
    unsigned short* q = encb + (size_t)b * NN * DD + d;
    float s = 0.f;
    for (int n = 0; n < NN; ++n) {
      float x = p[(size_t)n * DD];
      s += x;
      q[(size_t)n * DD] = f2bf(x);
    }
    const float mval = s * (1.0f / (float)NN);
    meanf[(size_t)b * DD + d] = mval;
    mbuf[(size_t)b * DD + d] = 0.f;
    x2_0[(size_t)b * 2048 + d] = f2bf(mval);
    x2_0[(size_t)b * 2048 + 1024 + d] = 0;
  }
}

// single-pass weight-norm: row in registers, one read of pred_v
__launch_bounds__(256)
__global__ void wn_kernel(const float* __restrict__ pred_v, const float* __restrict__ pred_g,
                          unsigned short* __restrict__ Wn) {
  int v = blockIdx.x, tid = threadIdx.x;
  f32x4 x = *reinterpret_cast<const f32x4*>(pred_v + (size_t)v * DD + tid * 4);
  float s = x[0] * x[0] + x[1] * x[1] + x[2] * x[2] + x[3] * x[3];
  #pragma unroll
  for (int o = 32; o; o >>= 1) s += __shfl_down(s, o);
  __shared__ float red[4];
  if ((tid & 63) == 0) red[tid >> 6] = s;
  __syncthreads();
  float inv = pred_g[v] * rsqrtf(red[0] + red[1] + red[2] + red[3]);
  u32x2 o = { pk2(x[0] * inv, x[1] * inv), pk2(x[2] * inv, x[3] * inv) };
  *reinterpret_cast<u32x2*>(Wn + (size_t)v * DD + tid * 4) = o;
}

extern "C" void kernel_launch(void* const* d_in, const int* in_sizes, int n_in,
                              void* d_out, int out_size, void* d_ws, size_t ws_size,
                              hipStream_t stream) {
  const float* enc      = (const float*)d_in[0];
  const int*   captions = (const int*)d_in[1];
  const int*   lengths  = (const int*)d_in[2];
  const float* embed_W  = (const float*)d_in[3];
  const float* W_ih     = (const float*)d_in[4];
  const float* b_ih     = (const float*)d_in[5];
  const float* W_hh     = (const float*)d_in[6];
  const float* b_hh     = (const float*)d_in[7];
  const float* Wq       = (const float*)d_in[8];
  const float* bq       = (const float*)d_in[9];
  const float* Wk       = (const float*)d_in[10];
  const float* bk       = (const float*)d_in[11];
  const float* Wv       = (const float*)d_in[12];
  const float* bv       = (const float*)d_in[13];
  const float* W_aoa    = (const float*)d_in[14];
  const float* b_aoa    = (const float*)d_in[15];
  const float* pred_v   = (const float*)d_in[16];
  const float* pred_g   = (const float*)d_in[17];
  const float* pred_b   = (const float*)d_in[18];
  float* out = (float*)d_out;

  char* base = (char*)d_ws;
  size_t off = 0;
  auto alloc = [&](size_t bytes) -> char* {
    char* p = base + off;
    off = (off + bytes + 255) & ~(size_t)255;
    return p;
  };
  unsigned short* KV     = (unsigned short*)alloc((size_t)BB * NN * 2048 * 2);
  unsigned short* WcatI  = (unsigned short*)alloc((size_t)4096 * 3072 * 2);
  unsigned short* WaoaI  = (unsigned short*)alloc((size_t)2048 * 2048 * 2);
  unsigned short* Wq_b   = (unsigned short*)alloc((size_t)DD * DD * 2);
  unsigned short* Wkv_b  = (unsigned short*)alloc((size_t)2048 * 1024 * 2);
  float* bcombI          = (float*)alloc(4096 * 4);
  float* baoaI           = (float*)alloc(2048 * 4);
  float* bkv             = (float*)alloc(2048 * 4);
  float* meanf           = (float*)alloc((size_t)BB * DD * 4);
  float* mbuf            = (float*)alloc((size_t)BB * DD * 4);
  unsigned short* embAll = (unsigned short*)alloc((size_t)TT * BB * DD * 2);
  unsigned short* x2     = (unsigned short*)alloc((size_t)2 * BB * 2048 * 2);
  // union: encb (precompute only) | { Eall, predinAll, xaoa, qbuf } (loop); Wn overlays dead Eall.
  char* uni = alloc((size_t)BB * NN * DD * 2);   // 51.4 MB
  unsigned short* encb = (unsigned short*)uni;
  size_t ua = 0;
  auto carve = [&](size_t b) -> char* { char* p = uni + ua; ua = (ua + b + 255) & ~(size_t)255; return p; };
  float* Eall               = (float*)carve((size_t)TT * BB * 4096 * 4);   // 41.9 MB
  unsigned short* predinAll = (unsigned short*)carve((size_t)TT * BB * DD * 2);
  unsigned short* xaoa      = (unsigned short*)carve((size_t)BB * 2048 * 2);
  float* qbuf               = (float*)carve((size_t)BB * DD * 4);
  unsigned short* Wn_b      = (unsigned short*)uni;                        // 20.5 MB over Eall
  if (off > ws_size || ua > (size_t)BB * NN * DD * 2) return;

  // NOTE: encb (uni base) is consumed by kv_eall (KV part) while Eall (also uni base)
  // is written by the same launch. Eall overlaps encb's first 41.9 MB. This is a
  // read/write hazard WITHIN one kernel -> NOT safe. Place Eall AFTER encb instead:
  // redo the union so encb and Eall coexist during kv_eall.
  // (Handled below: re-carve with encb first, Eall after.)
  {
    ua = 0;
    encb = (unsigned short*)carve((size_t)BB * NN * DD * 2);               // 51.4 MB
    Eall = (float*)alloc((size_t)TT * BB * 4096 * 4);                      // 41.9 MB (separate)
    predinAll = (unsigned short*)alloc((size_t)TT * BB * DD * 2);
    xaoa      = (unsigned short*)alloc((size_t)BB * 2048 * 2);
    qbuf      = (float*)alloc((size_t)BB * DD * 4);
    Wn_b      = (unsigned short*)uni;   // overlays encb, which is dead after kv_eall
    if (off > ws_size) return;
  }

  // ---- precompute (1 launch) ----
  prep_kernel<<<22544, 256, 0, stream>>>(W_ih, W_hh, Wq, W_aoa, Wk, Wv,
                                         b_ih, b_hh, b_aoa, bk, bv,
                                         embed_W, captions, enc,
                                         WcatI, Wq_b, WaoaI, Wkv_b,
                                         bcombI, baoaI, bkv, embAll,
                                         meanf, encb, mbuf, x2);
  // ---- merged KV projection + Eall (1 launch) ----
  kv_eall_kernel<<<3776, 256, 0, stream>>>(encb, Wkv_b, bkv, KV, embAll, WcatI, Eall);

  // ---- 20 recurrent steps (4 kernels/step, BM=64 + K2B single-barrier pipeline) ----
  for (int t = 0; t < TT; ++t) {
    unsigned short* xc = x2 + (size_t)(t & 1) * BB * 2048;
    unsigned short* xn = x2 + (size_t)((t + 1) & 1) * BB * 2048;
    gemmp<64, 32, 3, 6, false, true><<<256, 256, 0, stream>>>(xc, 2048, WcatI + 1024, 3072, 32, 4096, 128, bcombI,
                                                              Eall + (size_t)t * BB * 4096, nullptr, mbuf, nullptr, xaoa, xn, nullptr);
    gemmp<64, 32, 0, 6, false, true><<<64, 256, 0, stream>>>(xaoa + 1024, 2048, Wq_b, 1024, 16, 1024, 32, nullptr,
                                                             qbuf, nullptr, nullptr, nullptr, nullptr, nullptr, nullptr);
    attn_kernel<<<BB * NHH, 256, 0, stream>>>(qbuf, bq, KV, xaoa);
    gemmp<64, 32, 4, 6, false, true><<<128, 256, 0, stream>>>(xaoa, 2048, WaoaI, 2048, 32, 2048, 64, baoaI,
                                                              nullptr, predinAll + (size_t)t * BB * DD, nullptr, meanf, nullptr, xn, nullptr);
  }

  // ---- weight-norm (Wn overlays dead encb) + batched vocab GEMM ----
  wn_kernel<<<VV, 256, 0, stream>>>(pred_v, pred_g, Wn_b);
  gemmp<128, 128, 2, 2, true><<<1580, 256, 0, stream>>>(predinAll, 1024, Wn_b, 1024, 16, VV, 79, pred_b,
                                                        out, nullptr, nullptr, nullptr, nullptr, nullptr, lengths);
}

// Round 16
// 1148.463 us; speedup vs baseline: 1.0182x; 1.0182x over previous
//
#include <hip/hip_runtime.h>
#include <hip/hip_bf16.h>
#include <cstdint>

#define BB 128
#define TT 20
#define VV 10000
#define DD 1024
#define NHH 8
#define DHH 128
#define NN 196

typedef float f32x4 __attribute__((ext_vector_type(4)));
typedef __bf16 bf16x8 __attribute__((ext_vector_type(8)));
typedef unsigned int u32x4 __attribute__((ext_vector_type(4)));
typedef unsigned int u32x2 __attribute__((ext_vector_type(2)));

__device__ __forceinline__ unsigned short f2bf(float x) {
  unsigned u = __float_as_uint(x);
  u += 0x7FFFu + ((u >> 16) & 1u);
  return (unsigned short)(u >> 16);
}
__device__ __forceinline__ float bf2f(unsigned short h) {
  return __uint_as_float(((unsigned)h) << 16);
}
__device__ __forceinline__ float sigm(float x) { return 1.f / (1.f + __expf(-x)); }
__device__ __forceinline__ unsigned pk2(float lo, float hi) {
  return (unsigned)f2bf(lo) | ((unsigned)f2bf(hi) << 16);
}
__device__ __forceinline__ int xcd_swz(int orig, int nb) {
  int q = nb >> 3, r = nb & 7;
  int x = orig & 7, i = orig >> 3;
  return (x < r ? x * (q + 1) : r * (q + 1) + (x - r) * q) + i;
}
__device__ __forceinline__ void gl16(const void* g, void* l) {
  __builtin_amdgcn_global_load_lds((const __attribute__((address_space(1))) void*)g,
                                   (__attribute__((address_space(3))) void*)l, 16, 0, 0);
}

template<int N> __device__ __forceinline__ void waitvm() {
  if constexpr (N == 0)       asm volatile("s_waitcnt vmcnt(0)" ::: "memory");
  else if constexpr (N == 3)  asm volatile("s_waitcnt vmcnt(3)" ::: "memory");
  else if constexpr (N == 5)  asm volatile("s_waitcnt vmcnt(5)" ::: "memory");
  else if constexpr (N == 6)  asm volatile("s_waitcnt vmcnt(6)" ::: "memory");
  else if constexpr (N == 8)  asm volatile("s_waitcnt vmcnt(8)" ::: "memory");
  else if constexpr (N == 10) asm volatile("s_waitcnt vmcnt(10)" ::: "memory");
  else if constexpr (N == 12) asm volatile("s_waitcnt vmcnt(12)" ::: "memory");
  else if constexpr (N == 16) asm volatile("s_waitcnt vmcnt(16)" ::: "memory");
}
#define LGKM0()  asm volatile("s_waitcnt lgkmcnt(0)" ::: "memory")
#define SCHED0() __builtin_amdgcn_sched_barrier(0)

// ---- unified deep-pipelined GEMM: C[M,N] = A[M,K] @ W[N,:]^T, BM in {64,128}, BK=64.
// MODE 0: fp32 out (ldc=N)
// MODE 2: vocab batched rows=(t*128+b) + mask
// MODE 3: gates + Eall add + fused LSTM (W 32-col gate-interleaved)
// MODE 4: aoa + fused GLU (W 32-col half-interleaved)
// MODE 5: fp32 partials, split-K x2 (grid = 2 x 2rowtiles x ncol; out + split*128*N)
// RF: row-fastest wg mapping. K2: 2 K-tiles/iter, single barrier (DEP=6, stage dist 4).
template<int BM, int BN, int MODE, int DEP, bool RF, bool K2 = false>
__launch_bounds__(256)
__global__ void gemmp(const unsigned short* __restrict__ A, int lda,
                      const unsigned short* __restrict__ W, int ldw,
                      int nkt, int N, int ncol,
                      const float* __restrict__ bias,
                      float* __restrict__ outF, unsigned short* __restrict__ outB,
                      float* __restrict__ mbuf, const float* __restrict__ meanf,
                      unsigned short* __restrict__ xaoa, unsigned short* __restrict__ xn2,
                      const int* __restrict__ lengths)
{
  constexpr int SZA = BM * 128;
  constexpr int SZB = BN * 128;
  constexpr int NJ = BN / 16;
  constexpr int MI = BM / 64;
  constexpr int S = BM / 32 + BN / 32;
  __shared__ char smem[DEP * (SZA + SZB)];

  const int nb = gridDim.x;
  const int wg = xcd_swz(blockIdx.x, nb);
  int xi, rowt, ksplit = 0;
  if (MODE == 5) {
    const int inner = wg % (2 * ncol);
    ksplit = wg / (2 * ncol);
    xi = inner % ncol; rowt = inner / ncol;
  } else if (RF) { const int nrow = nb / ncol; rowt = wg % nrow; xi = wg / nrow; }
  else           { xi = wg % ncol; rowt = wg / ncol; }
  const int colbase = xi * BN;
  const int rowbase = rowt * BM;
  const int k0base = (MODE == 5) ? ksplit * nkt * 64 : 0;
  const int tid = threadIdx.x;
  const int lane = tid & 63, wv = tid >> 6;
  const int wrow = wv * (BM / 4);
  const int lr = lane & 15;
  const int srow = lane >> 3;
  const int schunk = ((lane & 7) ^ srow) * 8;

  auto stage = [&](int t, int buf) {
    char* sA = smem + buf * (SZA + SZB);
    char* sB = sA + SZA;
    const int k0 = k0base + (t << 6);
    #pragma unroll
    for (int s = 0; s < BM / 32; ++s) {
      const int rb = s * 32 + wv * 8;
      gl16(A + (size_t)(rowbase + rb + srow) * lda + k0 + schunk, sA + rb * 128);
    }
    #pragma unroll
    for (int s = 0; s < BN / 32; ++s) {
      const int rb = s * 32 + wv * 8;
      int br = colbase + rb + srow;
      if (MODE == 2) br = br < N ? br : N - 1;
      gl16(W + (size_t)br * ldw + k0 + schunk, sB + rb * 128);
    }
  };

  f32x4 acc[MI][NJ];
  const f32x4 zero = {0.f, 0.f, 0.f, 0.f};
  #pragma unroll
  for (int i = 0; i < MI; ++i)
    #pragma unroll
    for (int j = 0; j < NJ; ++j) acc[i][j] = zero;

  #pragma unroll
  for (int t = 0; t < (K2 ? 4 : DEP); ++t) stage(t, t);

  const int axor = (lr & 7) << 4;
  const int ccol = (lane >> 4) * 16;

  if constexpr (K2) {
    for (int i = 0; i < nkt; i += 2) {
      if (i + 2 < nkt) waitvm<2 * S>(); else waitvm<0>();
      __builtin_amdgcn_s_barrier();     // protects bufs read in iteration n-1
      SCHED0();
      if (i + 4 < nkt) {
        stage(i + 4, (i + 4) % DEP);
        stage(i + 5, (i + 5) % DEP);
      }
      bf16x8 af[2][MI][2], bfr[2][NJ][2];
      #pragma unroll
      for (int u = 0; u < 2; ++u) {
        const char* sA = smem + ((i + u) % DEP) * (SZA + SZB);
        const char* sB = sA + SZA;
        #pragma unroll
        for (int ii = 0; ii < MI; ++ii)
          #pragma unroll
          for (int kk = 0; kk < 2; ++kk)
            af[u][ii][kk] = *reinterpret_cast<const bf16x8*>(
                sA + (wrow + ii * 16 + lr) * 128 + ((kk * 64 + ccol) ^ axor));
        #pragma unroll
        for (int j = 0; j < NJ; ++j)
          #pragma unroll
          for (int kk = 0; kk < 2; ++kk)
            bfr[u][j][kk] = *reinterpret_cast<const bf16x8*>(
                sB + (j * 16 + lr) * 128 + ((kk * 64 + ccol) ^ axor));
      }
      LGKM0();
      SCHED0();
      #pragma unroll
      for (int u = 0; u < 2; ++u)
        #pragma unroll
        for (int kk = 0; kk < 2; ++kk)
          #pragma unroll
          for (int ii = 0; ii < MI; ++ii)
            #pragma unroll
            for (int j = 0; j < NJ; ++j)
              acc[ii][j] = __builtin_amdgcn_mfma_f32_16x16x32_bf16(af[u][ii][kk], bfr[u][j][kk], acc[ii][j], 0, 0, 0);
    }
  } else {
    int buf = 0;
    for (int i = 0; i < nkt; ++i) {
      const int rem = nkt - 1 - i;
      if (rem >= DEP - 1)            waitvm<S * (DEP - 1)>();
      else if (DEP > 2 && rem == 1)  waitvm<S>();
      else                           waitvm<0>();
      __builtin_amdgcn_s_barrier();
      SCHED0();
      const char* sA = smem + buf * (SZA + SZB);
      const char* sB = sA + SZA;
      bf16x8 af[MI][2], bfr[NJ][2];
      #pragma unroll
      for (int ii = 0; ii < MI; ++ii)
        #pragma unroll
        for (int kk = 0; kk < 2; ++kk)
          af[ii][kk] = *reinterpret_cast<const bf16x8*>(
              sA + (wrow + ii * 16 + lr) * 128 + ((kk * 64 + ccol) ^ axor));
      #pragma unroll
      for (int j = 0; j < NJ; ++j)
        #pragma unroll
        for (int kk = 0; kk < 2; ++kk)
          bfr[j][kk] = *reinterpret_cast<const bf16x8*>(
              sB + (j * 16 + lr) * 128 + ((kk * 64 + ccol) ^ axor));
      LGKM0();
      SCHED0();
      __builtin_amdgcn_s_barrier();
      SCHED0();
      if (i + DEP < nkt) stage(i + DEP, buf);
      #pragma unroll
      for (int kk = 0; kk < 2; ++kk)
        #pragma unroll
        for (int ii = 0; ii < MI; ++ii)
          #pragma unroll
          for (int j = 0; j < NJ; ++j)
            acc[ii][j] = __builtin_amdgcn_mfma_f32_16x16x32_bf16(af[ii][kk], bfr[j][kk], acc[ii][j], 0, 0, 0);
      buf = (buf == DEP - 1) ? 0 : buf + 1;
    }
  }

  const int rg4 = (lane >> 4) * 4;

  if constexpr (MODE == 0 || MODE == 5) {
    float* dst = (MODE == 5) ? outF + (size_t)ksplit * 128 * N : outF;
    #pragma unroll
    for (int ii = 0; ii < MI; ++ii)
      #pragma unroll
      for (int j = 0; j < NJ; ++j) {
        const int gcol = colbase + j * 16 + lr;
        #pragma unroll
        for (int r = 0; r < 4; ++r)
          dst[(size_t)(rowbase + wrow + ii * 16 + rg4 + r) * N + gcol] = acc[ii][j][r];
      }
  } else if constexpr (MODE == 2) {
    #pragma unroll
    for (int ii = 0; ii < MI; ++ii)
      #pragma unroll
      for (int j = 0; j < NJ; ++j) {
        const int gcol = colbase + j * 16 + lr;
        if (gcol >= N) continue;
        const float bv = bias[gcol];
        #pragma unroll
        for (int r = 0; r < 4; ++r) {
          const int gr = rowbase + wrow + ii * 16 + rg4 + r;   // t*128 + b
          const int tt = gr >> 7, bb = gr & 127;
          outF[((size_t)bb * TT + tt) * VV + gcol] =
              (tt < lengths[bb]) ? acc[ii][j][r] + bv : 0.f;
        }
      }
  } else if constexpr (MODE == 3) {
    const float b0 = bias[colbase + lr], b1 = bias[colbase + 16 + lr];
    float a0[MI][4], a1[MI][4];
    #pragma unroll
    for (int ii = 0; ii < MI; ++ii)
      #pragma unroll
      for (int r = 0; r < 4; ++r) {
        const int grow = rowbase + wrow + ii * 16 + rg4 + r;
        a0[ii][r] = acc[ii][0][r] + b0 + outF[(size_t)grow * 4096 + colbase + lr];
        a1[ii][r] = acc[ii][1][r] + b1 + outF[(size_t)grow * 4096 + colbase + 16 + lr];
      }
    const int d = (colbase >> 2) + (lr & 7);
    #pragma unroll
    for (int ii = 0; ii < MI; ++ii)
      #pragma unroll
      for (int r = 0; r < 4; ++r) {
        const float fg = __shfl_xor(a0[ii][r], 8);
        const float og = __shfl_xor(a1[ii][r], 8);
        if (lr < 8) {
          const int grow = rowbase + wrow + ii * 16 + rg4 + r;
          const float m2 = sigm(fg) * mbuf[(size_t)grow * DD + d] + sigm(a0[ii][r]) * tanhf(a1[ii][r]);
          const float h2 = sigm(og) * tanhf(m2);
          mbuf[(size_t)grow * DD + d] = m2;
          const unsigned short hb = f2bf(h2);
          xaoa[(size_t)grow * 2048 + 1024 + d] = hb;
          xn2[(size_t)grow * 2048 + 1024 + d] = hb;
        }
      }
  } else {  // MODE 4: aoa + GLU
    const int d = (colbase >> 1) + lr;
    const float b0 = bias[colbase + lr], b1 = bias[colbase + 16 + lr];
    #pragma unroll
    for (int ii = 0; ii < MI; ++ii)
      #pragma unroll
      for (int r = 0; r < 4; ++r) {
        const int grow = rowbase + wrow + ii * 16 + rg4 + r;
        const float av1 = acc[ii][0][r] + b0;
        const float av2 = acc[ii][1][r] + b1;
        const float c2 = av1 * sigm(av2);
        outB[(size_t)grow * DD + d] = f2bf(c2);
        xn2[(size_t)grow * 2048 + d] = f2bf(meanf[(size_t)grow * DD + d] + c2);
      }
  }
}

// ---- shared 128x128 DEP=2 nkt=16 GEMM core for the merged KV+Eall kernel ----
__device__ __forceinline__ void gemm_core128(const unsigned short* __restrict__ A, int lda,
                                             const unsigned short* __restrict__ W, int ldw,
                                             int rowbase, int colbase, char* smem,
                                             f32x4 (&acc)[2][8])
{
  constexpr int SZA = 128 * 128, SZB = 128 * 128;
  const int tid = threadIdx.x;
  const int lane = tid & 63, wv = tid >> 6;
  const int wrow = wv * 32;
  const int lr = lane & 15;
  const int srow = lane >> 3;
  const int schunk = ((lane & 7) ^ srow) * 8;

  auto stage = [&](int t, int buf) {
    char* sA = smem + buf * (SZA + SZB);
    char* sB = sA + SZA;
    const int k0 = t << 6;
    #pragma unroll
    for (int s = 0; s < 4; ++s) {
      const int rb = s * 32 + wv * 8;
      gl16(A + (size_t)(rowbase + rb + srow) * lda + k0 + schunk, sA + rb * 128);
    }
    #pragma unroll
    for (int s = 0; s < 4; ++s) {
      const int rb = s * 32 + wv * 8;
      gl16(W + (size_t)(colbase + rb + srow) * ldw + k0 + schunk, sB + rb * 128);
    }
  };

  const f32x4 zero = {0.f, 0.f, 0.f, 0.f};
  #pragma unroll
  for (int i = 0; i < 2; ++i)
    #pragma unroll
    for (int j = 0; j < 8; ++j) acc[i][j] = zero;

  stage(0, 0); stage(1, 1);
  const int axor = (lr & 7) << 4;
  const int ccol = (lane >> 4) * 16;
  int buf = 0;
  for (int i = 0; i < 16; ++i) {
    if (i < 15) waitvm<8>(); else waitvm<0>();
    __builtin_amdgcn_s_barrier();
    SCHED0();
    const char* sA = smem + buf * (SZA + SZB);
    const char* sB = sA + SZA;
    bf16x8 af[2][2], bfr[8][2];
    #pragma unroll
    for (int ii = 0; ii < 2; ++ii)
      #pragma unroll
      for (int kk = 0; kk < 2; ++kk)
        af[ii][kk] = *reinterpret_cast<const bf16x8*>(
            sA + (wrow + ii * 16 + lr) * 128 + ((kk * 64 + ccol) ^ axor));
    #pragma unroll
    for (int j = 0; j < 8; ++j)
      #pragma unroll
      for (int kk = 0; kk < 2; ++kk)
        bfr[j][kk] = *reinterpret_cast<const bf16x8*>(
            sB + (j * 16 + lr) * 128 + ((kk * 64 + ccol) ^ axor));
    LGKM0();
    SCHED0();
    __builtin_amdgcn_s_barrier();
    SCHED0();
    if (i + 2 < 16) stage(i + 2, buf);
    #pragma unroll
    for (int kk = 0; kk < 2; ++kk)
      #pragma unroll
      for (int ii = 0; ii < 2; ++ii)
        #pragma unroll
        for (int j = 0; j < 8; ++j)
          acc[ii][j] = __builtin_amdgcn_mfma_f32_16x16x32_bf16(af[ii][kk], bfr[j][kk], acc[ii][j], 0, 0, 0);
    buf ^= 1;
  }
}

// ---- merged KV projection (blocks 0..3135) + Eall GEMM (blocks 3136..3775) ----
__launch_bounds__(256)
__global__ void kv_eall_kernel(const unsigned short* __restrict__ encb,
                               const unsigned short* __restrict__ Wkv,
                               const float* __restrict__ bkv,
                               unsigned short* __restrict__ KV,
                               const unsigned short* __restrict__ embAll,
                               const unsigned short* __restrict__ WcatI,
                               float* __restrict__ Eall)
{
  __shared__ char smem[2 * (128 * 128 + 128 * 128)];   // 64 KB
  f32x4 acc[2][8];
  const int tid = threadIdx.x;
  const int lane = tid & 63, wv = tid >> 6;
  const int wrow = wv * 32, lr = lane & 15;
  const int rg4 = (lane >> 4) * 4;

  if (blockIdx.x < 3136) {
    const int wg = xcd_swz(blockIdx.x, 3136);
    const int xi = wg % 16, rowt = wg / 16;
    const int colbase = xi * 128, rowbase = rowt * 128;
    gemm_core128(encb, 1024, Wkv, 1024, rowbase, colbase, smem, acc);
    #pragma unroll
    for (int ii = 0; ii < 2; ++ii)
      #pragma unroll
      for (int j = 0; j < 8; ++j) {
        const int gcol = colbase + j * 16 + lr;
        const float bv = bkv[gcol];
        #pragma unroll
        for (int r = 0; r < 4; ++r)
          KV[(size_t)(rowbase + wrow + ii * 16 + rg4 + r) * 2048 + gcol] = f2bf(acc[ii][j][r] + bv);
      }
  } else {
    const int wg = xcd_swz(blockIdx.x - 3136, 640);
    const int rowt = wg % 20, xi = wg / 20;
    const int colbase = xi * 128, rowbase = rowt * 128;
    gemm_core128(embAll, 1024, WcatI, 3072, rowbase, colbase, smem, acc);
    #pragma unroll
    for (int ii = 0; ii < 2; ++ii)
      #pragma unroll
      for (int j = 0; j < 8; ++j) {
        const int gcol = colbase + j * 16 + lr;
        #pragma unroll
        for (int r = 0; r < 4; ++r)
          Eall[(size_t)(rowbase + wrow + ii * 16 + rg4 + r) * 4096 + gcol] = acc[ii][j][r];
      }
  }
}

// ---- attention (grid 1024 = (b,h)), wave-parallel softmax, dual-acc PV; sums 2 q-partials ----
__launch_bounds__(256)
__global__ void attn_kernel(const float* __restrict__ qbuf, const float* __restrict__ bq,
                            const unsigned short* __restrict__ KV, unsigned short* __restrict__ xaoa) {
  const int bh = blockIdx.x, b = bh >> 3, h = bh & 7;
  const int tid = threadIdx.x;
  const int lane = tid & 63, wv = tid >> 6;
  __shared__ float qs[DHH];
  __shared__ float sc[NN + 4];
  __shared__ float pvred[2][DHH];
  __shared__ float redm[4], reds[4];
  if (tid < DHH)
    qs[tid] = bq[h * DHH + tid] + qbuf[(size_t)b * DD + h * DHH + tid]
            + qbuf[(size_t)BB * DD + (size_t)b * DD + h * DHH + tid];
  __syncthreads();
  if (tid < NN) {
    const unsigned short* kr = KV + ((size_t)(b * NN + tid)) * 2048 + h * DHH;
    float a = 0.f;
    #pragma unroll
    for (int j = 0; j < 16; ++j) {
      u32x4 kk = *reinterpret_cast<const u32x4*>(kr + j * 8);
      #pragma unroll
      for (int w = 0; w < 4; ++w) {
        a += bf2f((unsigned short)(kk[w] & 0xffffu)) * qs[j * 8 + w * 2]
           + bf2f((unsigned short)(kk[w] >> 16)) * qs[j * 8 + w * 2 + 1];
      }
    }
    sc[tid] = a * 0.08838834764831845f;
  }
  __syncthreads();
  float v = (tid < NN) ? sc[tid] : -1e30f;
  #pragma unroll
  for (int o = 32; o; o >>= 1) v = fmaxf(v, __shfl_xor(v, o));
  if (lane == 0) redm[wv] = v;
  __syncthreads();
  const float mx = fmaxf(fmaxf(redm[0], redm[1]), fmaxf(redm[2], redm[3]));
  float e = 0.f;
  if (tid < NN) { e = __expf(sc[tid] - mx); sc[tid] = e; }
  float s = e;
  #pragma unroll
  for (int o = 32; o; o >>= 1) s += __shfl_xor(s, o);
  if (lane == 0) reds[wv] = s;
  __syncthreads();
  const float inv = 1.f / (reds[0] + reds[1] + reds[2] + reds[3]);
  const int d = tid & 127, half = tid >> 7;
  const unsigned short* vr = KV + ((size_t)(b * NN + half * 98)) * 2048 + 1024 + h * DHH + d;
  const float* pr = sc + half * 98;
  float a0 = 0.f, a1 = 0.f;
  #pragma unroll 7
  for (int n = 0; n < 98; n += 2) {
    a0 += pr[n]     * bf2f(vr[(size_t)n * 2048]);
    a1 += pr[n + 1] * bf2f(vr[(size_t)(n + 1) * 2048]);
  }
  pvred[half][d] = a0 + a1;
  __syncthreads();
  if (tid < DHH)
    xaoa[(size_t)b * 2048 + h * DHH + tid] = f2bf((pvred[0][tid] + pvred[1][tid]) * inv);
}

// ---- fused prep: weights/bias/embedding/meanconv+init, one launch, range-dispatched ----
__launch_bounds__(256)
__global__ void prep_kernel(const float* __restrict__ W_ih, const float* __restrict__ W_hh,
                            const float* __restrict__ Wq, const float* __restrict__ W_aoa,
                            const float* __restrict__ Wk, const float* __restrict__ Wv,
                            const float* __restrict__ b_ih, const float* __restrict__ b_hh,
                            const float* __restrict__ b_aoa, const float* __restrict__ bk,
                            const float* __restrict__ bv,
                            const float* __restrict__ embed_W, const int* __restrict__ captions,
                            const float* __restrict__ enc,
                            unsigned short* __restrict__ WcatI, unsigned short* __restrict__ Wq_b,
                            unsigned short* __restrict__ WaoaI, unsigned short* __restrict__ Wkv_b,
                            float* __restrict__ bcombI, float* __restrict__ baoaI,
                            float* __restrict__ bkv,
                            unsigned short* __restrict__ embAll,
                            float* __restrict__ meanf, unsigned short* __restrict__ encb,
                            float* __restrict__ mbuf, unsigned short* __restrict__ x2_0)
{
  const int bid = blockIdx.x, tid = threadIdx.x;
  if (bid < 12288) {
    int i = bid * 256 + tid;
    int rp = i / 768, c4 = (i - rp * 768) * 4;
    int rem = rp & 31, g = rem >> 3, d = (rp >> 5) * 8 + (rem & 7);
    int orig = g * 1024 + d;
    const float* src = (c4 < 2048) ? (W_ih + (size_t)orig * 2048 + c4)
                                   : (W_hh + (size_t)orig * 1024 + (c4 - 2048));
    f32x4 vv = *reinterpret_cast<const f32x4*>(src);
    u32x2 o = { pk2(vv[0], vv[1]), pk2(vv[2], vv[3]) };
    *reinterpret_cast<u32x2*>(WcatI + (size_t)rp * 3072 + c4) = o;
  } else if (bid < 13312) {
    int i = (bid - 12288) * 256 + tid;
    f32x4 vv = *reinterpret_cast<const f32x4*>(Wq + (size_t)i * 4);
    u32x2 o = { pk2(vv[0], vv[1]), pk2(vv[2], vv[3]) };
    *reinterpret_cast<u32x2*>(Wq_b + (size_t)i * 4) = o;
  } else if (bid < 17408) {
    int i = (bid - 13312) * 256 + tid;
    int rp = i >> 9, c4 = (i & 511) * 4;
    int rem = rp & 31, half = rem >> 4, d = (rp >> 5) * 16 + (rem & 15);
    int orig = half * 1024 + d;
    f32x4 vv = *reinterpret_cast<const f32x4*>(W_aoa + (size_t)orig * 2048 + c4);
    u32x2 o = { pk2(vv[0], vv[1]), pk2(vv[2], vv[3]) };
    *reinterpret_cast<u32x2*>(WaoaI + (size_t)rp * 2048 + c4) = o;
  } else if (bid < 19456) {
    int i = (bid - 17408) * 256 + tid;
    int row = i >> 8, c4 = (i & 255) << 2;
    const float* src = (row < 1024) ? (Wk + (size_t)row * 1024 + c4)
                                    : (Wv + (size_t)(row - 1024) * 1024 + c4);
    f32x4 vv = *reinterpret_cast<const f32x4*>(src);
    u32x2 o = { pk2(vv[0], vv[1]), pk2(vv[2], vv[3]) };
    *reinterpret_cast<u32x2*>(Wkv_b + (size_t)row * 1024 + c4) = o;
  } else if (bid < 19472) {
    int i = (bid - 19456) * 256 + tid;
    {
      int rem = i & 31, g = rem >> 3, d = (i >> 5) * 8 + (rem & 7);
      int orig = g * 1024 + d;
      bcombI[i] = b_ih[orig] + b_hh[orig];
    }
    if (i < 2048) {
      int rem = i & 31, half = rem >> 4, d = (i >> 5) * 16 + (rem & 15);
      baoaI[i] = b_aoa[half * 1024 + d];
      bkv[i] = (i < 1024) ? bk[i] : bv[i - 1024];
    }
  } else if (bid < 22032) {
    int i = (bid - 19472) * 256 + tid;
    int j4 = (i & 255) << 2, b = (i >> 8) & 127, t = i >> 15;
    int tok = captions[b * TT + t];
    f32x4 vv = *reinterpret_cast<const f32x4*>(embed_W + (size_t)tok * DD + j4);
    u32x2 o = { pk2(vv[0], vv[1]), pk2(vv[2], vv[3]) };
    *reinterpret_cast<u32x2*>(embAll + ((size_t)t * BB + b) * DD + j4) = o;
  } else {
    int rb = bid - 22032;
    int b = rb >> 2, d = (rb & 3) * 256 + tid;
    const float* p = enc + (size_t)b * NN * DD + d;
    unsigned short* q = encb + (size_t)b * NN * DD + d;
    float s = 0.f;
    for (int n = 0; n < NN; ++n) {
      float x = p[(size_t)n * DD];
      s += x;
      q[(size_t)n * DD] = f2bf(x);
    }
    const float mval = s * (1.0f / (float)NN);
    meanf[(size_t)b * DD + d] = mval;
    mbuf[(size_t)b * DD + d] = 0.f;
    x2_0[(size_t)b * 2048 + d] = f2bf(mval);
    x2_0[(size_t)b * 2048 + 1024 + d] = 0;
  }
}

// single-pass weight-norm: row in registers, one read of pred_v
__launch_bounds__(256)
__global__ void wn_kernel(const float* __restrict__ pred_v, const float* __restrict__ pred_g,
                          unsigned short* __restrict__ Wn) {
  int v = blockIdx.x, tid = threadIdx.x;
  f32x4 x = *reinterpret_cast<const f32x4*>(pred_v + (size_t)v * DD + tid * 4);
  float s = x[0] * x[0] + x[1] * x[1] + x[2] * x[2] + x[3] * x[3];
  #pragma unroll
  for (int o = 32; o; o >>= 1) s += __shfl_down(s, o);
  __shared__ float red[4];
  if ((tid & 63) == 0) red[tid >> 6] = s;
  __syncthreads();
  float inv = pred_g[v] * rsqrtf(red[0] + red[1] + red[2] + red[3]);
  u32x2 o = { pk2(x[0] * inv, x[1] * inv), pk2(x[2] * inv, x[3] * inv) };
  *reinterpret_cast<u32x2*>(Wn + (size_t)v * DD + tid * 4) = o;
}

extern "C" void kernel_launch(void* const* d_in, const int* in_sizes, int n_in,
                              void* d_out, int out_size, void* d_ws, size_t ws_size,
                              hipStream_t stream) {
  const float* enc      = (const float*)d_in[0];
  const int*   captions = (const int*)d_in[1];
  const int*   lengths  = (const int*)d_in[2];
  const float* embed_W  = (const float*)d_in[3];
  const float* W_ih     = (const float*)d_in[4];
  const float* b_ih     = (const float*)d_in[5];
  const float* W_hh     = (const float*)d_in[6];
  const float* b_hh     = (const float*)d_in[7];
  const float* Wq       = (const float*)d_in[8];
  const float* bq       = (const float*)d_in[9];
  const float* Wk       = (const float*)d_in[10];
  const float* bk       = (const float*)d_in[11];
  const float* Wv       = (const float*)d_in[12];
  const float* bv       = (const float*)d_in[13];
  const float* W_aoa    = (const float*)d_in[14];
  const float* b_aoa    = (const float*)d_in[15];
  const float* pred_v   = (const float*)d_in[16];
  const float* pred_g   = (const float*)d_in[17];
  const float* pred_b   = (const float*)d_in[18];
  float* out = (float*)d_out;

  char* base = (char*)d_ws;
  size_t off = 0;
  auto alloc = [&](size_t bytes) -> char* {
    char* p = base + off;
    off = (off + bytes + 255) & ~(size_t)255;
    return p;
  };
  unsigned short* KV     = (unsigned short*)alloc((size_t)BB * NN * 2048 * 2);
  unsigned short* WcatI  = (unsigned short*)alloc((size_t)4096 * 3072 * 2);
  unsigned short* WaoaI  = (unsigned short*)alloc((size_t)2048 * 2048 * 2);
  unsigned short* Wq_b   = (unsigned short*)alloc((size_t)DD * DD * 2);
  unsigned short* Wkv_b  = (unsigned short*)alloc((size_t)2048 * 1024 * 2);
  float* bcombI          = (float*)alloc(4096 * 4);
  float* baoaI           = (float*)alloc(2048 * 4);
  float* bkv             = (float*)alloc(2048 * 4);
  float* meanf           = (float*)alloc((size_t)BB * DD * 4);
  float* mbuf            = (float*)alloc((size_t)BB * DD * 4);
  unsigned short* embAll = (unsigned short*)alloc((size_t)TT * BB * DD * 2);
  unsigned short* x2     = (unsigned short*)alloc((size_t)2 * BB * 2048 * 2);
  // encb coexists with Eall during kv_eall; Wn overlays dead encb after the loop starts.
  unsigned short* encb      = (unsigned short*)alloc((size_t)BB * NN * DD * 2);   // 51.4 MB
  float* Eall               = (float*)alloc((size_t)TT * BB * 4096 * 4);          // 41.9 MB
  unsigned short* predinAll = (unsigned short*)alloc((size_t)TT * BB * DD * 2);
  unsigned short* xaoa      = (unsigned short*)alloc((size_t)BB * 2048 * 2);
  float* qbuf               = (float*)alloc((size_t)2 * BB * DD * 4);
  unsigned short* Wn_b      = (unsigned short*)encb;   // overlays dead encb
  if (off > ws_size) return;

  // ---- precompute (1 launch) ----
  prep_kernel<<<22544, 256, 0, stream>>>(W_ih, W_hh, Wq, W_aoa, Wk, Wv,
                                         b_ih, b_hh, b_aoa, bk, bv,
                                         embed_W, captions, enc,
                                         WcatI, Wq_b, WaoaI, Wkv_b,
                                         bcombI, baoaI, bkv, embAll,
                                         meanf, encb, mbuf, x2);
  // ---- merged KV projection + Eall (1 launch) ----
  kv_eall_kernel<<<3776, 256, 0, stream>>>(encb, Wkv_b, bkv, KV, embAll, WcatI, Eall);

  // ---- 20 recurrent steps (4 kernels/step, BM=64 + K2B single-barrier pipeline) ----
  for (int t = 0; t < TT; ++t) {
    unsigned short* xc = x2 + (size_t)(t & 1) * BB * 2048;
    unsigned short* xn = x2 + (size_t)((t + 1) & 1) * BB * 2048;
    gemmp<64, 32, 3, 6, false, true><<<256, 256, 0, stream>>>(xc, 2048, WcatI + 1024, 3072, 32, 4096, 128, bcombI,
                                                              Eall + (size_t)t * BB * 4096, nullptr, mbuf, nullptr, xaoa, xn, nullptr);
    // q: split-K x2 -> grid 128 (2 splits x 2 rowtiles x 32 cols), nkt=8 each
    gemmp<64, 32, 5, 6, false, true><<<128, 256, 0, stream>>>(xaoa + 1024, 2048, Wq_b, 1024, 8, 1024, 32, nullptr,
                                                              qbuf, nullptr, nullptr, nullptr, nullptr, nullptr, nullptr);
    attn_kernel<<<BB * NHH, 256, 0, stream>>>(qbuf, bq, KV, xaoa);
    gemmp<64, 32, 4, 6, false, true><<<128, 256, 0, stream>>>(xaoa, 2048, WaoaI, 2048, 32, 2048, 64, baoaI,
                                                              nullptr, predinAll + (size_t)t * BB * DD, nullptr, meanf, nullptr, xn, nullptr);
  }

  // ---- weight-norm (overlays dead encb) + batched vocab GEMM ----
  wn_kernel<<<VV, 256, 0, stream>>>(pred_v, pred_g, Wn_b);
  gemmp<128, 128, 2, 2, true><<<1580, 256, 0, stream>>>(predinAll, 1024, Wn_b, 1024, 16, VV, 79, pred_b,
                                                        out, nullptr, nullptr, nullptr, nullptr, nullptr, lengths);
}